// Round 2
// baseline (446.078 us; speedup 1.0000x reference)
//
#include <hip/hip_runtime.h>
#include <cstdint>
#include <cstddef>

typedef unsigned short ushort_t;
typedef unsigned int   uint_t;

#define B_   8
#define T_   16
#define N_   196
#define C_   768
#define H_   12
#define C3_  2304
#define M_   25088   // B_*T_*N_

// spatial-attention tiling
#define NP_  208     // N padded to 13 tiles of 16
#define KS_  72      // K LDS row stride (elems): 144 B, 16B-aligned, 2-way alias
#define VS_  232     // V^T LDS row stride: 464 B, 16B-aligned, 2-way alias
#define PS_  232     // P LDS row stride

// temporal-attention tiling
#define TS_  40      // LDS row stride (elems): 80 B, 16B-aligned, 2-way alias

typedef __attribute__((ext_vector_type(8))) short short8;
typedef __attribute__((ext_vector_type(4))) float floatx4;

__device__ __forceinline__ float bf2f(ushort_t u) {
  return __uint_as_float(((uint_t)u) << 16);
}
__device__ __forceinline__ ushort_t f2bf(float f) {
  uint_t u = __float_as_uint(f);
  u += 0x7FFFu + ((u >> 16) & 1u);   // round-to-nearest-even
  return (ushort_t)(u >> 16);
}
__device__ __forceinline__ uint_t pack2(float a, float b) {
  return (uint_t)f2bf(a) | ((uint_t)f2bf(b) << 16);
}

// async global->LDS, 16 B per lane. LDS dest = wave-uniform base + lane*16.
__device__ __forceinline__ void gload_lds16(const ushort_t* g, ushort_t* l) {
  __builtin_amdgcn_global_load_lds(
      (const __attribute__((address_space(1))) uint_t*)g,
      (__attribute__((address_space(3))) uint_t*)l, 16, 0, 0);
}

// ---------------------------------------------------------------------------
// Fused prep (one dispatch instead of three):
//   blocks [0, 9408)        : x fp32 -> bf16, 8 elems/thread (19,267,584)
//   blocks [9408, 16320)    : W_qkv [768][2304] -> transposed bf16 [2304][768]
//   blocks [16320, 18624)   : W_proj [768][768] -> transposed bf16 [768][768]
// Transposes read strided fp32 (absorbed by L2: both W fit), write coalesced.
// ---------------------------------------------------------------------------
__global__ void fsta_prep(const float* __restrict__ x,
                          ushort_t* __restrict__ xbf,
                          const float* __restrict__ Wqkv,
                          ushort_t* __restrict__ WtQkv,
                          const float* __restrict__ Wproj,
                          ushort_t* __restrict__ WtProj)
{
  const int bid = blockIdx.x;
  const int tid = threadIdx.x;
  if (bid < 9408) {
    int i = (bid * 256 + tid) * 8;
    const float* f = x + i;
    uint4 u;
    u.x = pack2(f[0], f[1]); u.y = pack2(f[2], f[3]);
    u.z = pack2(f[4], f[5]); u.w = pack2(f[6], f[7]);
    *(uint4*)(xbf + i) = u;
  } else if (bid < 16320) {
    // W_qkv: R=768 rows, Cc=2304 cols; o indexes dst [Cc][R]
    int o = (bid - 9408) * 256 + tid;           // < 1,769,472
    int c = o / 768;
    int r = o - c * 768;
    WtQkv[o] = f2bf(Wqkv[(size_t)r * 2304 + c]);
  } else {
    int o = (bid - 16320) * 256 + tid;          // < 589,824
    int c = o / 768;
    int r = o - c * 768;
    WtProj[o] = f2bf(Wproj[(size_t)r * 768 + c]);
  }
}

// ---------------------------------------------------------------------------
// bf16 MFMA GEMM (m97 structure):  C[M,N] = A[M,K] @ Bt[N,K]^T (+ fp32 bias)
// 128x128 tile, BK=32, 4 waves, 4x4 of 16x16x32 MFMA per wave.
// Staging via global_load_lds width=16: LDS tiles are UNPADDED [128][32]
// (dest = wave-uniform base + lane*16 B, lane-contiguous layout mandatory).
// Bijective XCD-chunk swizzle on the linearized 2D grid (T1) so each XCD's
// resident blocks share a B-panel / neighboring A-panels in its private L2.
// ---------------------------------------------------------------------------
template <typename OutT>
__global__ __launch_bounds__(256) void fsta_gemm_bt(
    const ushort_t* __restrict__ A1,
    const ushort_t* __restrict__ Bt,
    const float* __restrict__ bias,
    OutT* __restrict__ Cout,
    int Ncols, int K)
{
  __shared__ ushort_t As[128 * 32];
  __shared__ ushort_t Bs[128 * 32];
  const int tid  = threadIdx.x;

  // XCD-aware swizzle (grids are 3528 / 1176 blocks, both divisible by 8)
  const int nbx = gridDim.x;
  const int nwg = nbx * gridDim.y;
  int lin = blockIdx.y * nbx + blockIdx.x;
  if ((nwg & 7) == 0) {
    const int cpx = nwg >> 3;
    lin = (lin & 7) * cpx + (lin >> 3);
  }
  const int m0 = (lin % nbx) * 128;
  const int n0 = (lin / nbx) * 128;

  const int lane = tid & 63;
  const int wv   = tid >> 6;
  const int wr   = (wv >> 1) * 64;
  const int wc   = (wv & 1) * 64;
  const int lrow = lane & 15;
  const int k8   = (lane >> 4) * 8;

  // staging coords: 4 lanes per row (16 B each), 16 rows per chunk
  const int srow = lane >> 2;          // 0..15
  const int scol = (lane & 3) * 8;     // 0,8,16,24

  floatx4 acc[4][4];
#pragma unroll
  for (int i = 0; i < 4; ++i)
#pragma unroll
    for (int j = 0; j < 4; ++j)
      acc[i][j] = (floatx4){0.f, 0.f, 0.f, 0.f};

  for (int k0 = 0; k0 < K; k0 += 32) {
#pragma unroll
    for (int i = 0; i < 2; ++i) {
      const int ch = wv * 2 + i;                    // 0..7
      const ushort_t* ga =
          A1 + (size_t)(m0 + ch * 16 + srow) * K + k0 + scol;
      gload_lds16(ga, &As[ch * 512]);               // 512 elems = 16 rows
      const ushort_t* gb =
          Bt + (size_t)(n0 + ch * 16 + srow) * K + k0 + scol;
      gload_lds16(gb, &Bs[ch * 512]);
    }
    __syncthreads();                                // drains vmcnt

    short8 af[4], bfr[4];
#pragma unroll
    for (int i = 0; i < 4; ++i)
      af[i] = *(const short8*)&As[(wr + i * 16 + lrow) * 32 + k8];
#pragma unroll
    for (int i = 0; i < 4; ++i)
      bfr[i] = *(const short8*)&Bs[(wc + i * 16 + lrow) * 32 + k8];

#pragma unroll
    for (int i = 0; i < 4; ++i)
#pragma unroll
      for (int j = 0; j < 4; ++j)
        acc[i][j] = __builtin_amdgcn_mfma_f32_16x16x32_bf16(
            af[i], bfr[j], acc[i][j], 0, 0, 0);
    __syncthreads();
  }

  const int qd = lane >> 4;
#pragma unroll
  for (int i = 0; i < 4; ++i) {
    int row = m0 + wr + i * 16 + qd * 4;
#pragma unroll
    for (int j = 0; j < 4; ++j) {
      int col = n0 + wc + j * 16 + lrow;
      float badd = bias ? bias[col] : 0.f;
#pragma unroll
      for (int r = 0; r < 4; ++r) {
        float v = acc[i][j][r] + badd;
        if constexpr (sizeof(OutT) == 4)
          Cout[(size_t)(row + r) * Ncols + col] = v;
        else
          Cout[(size_t)(row + r) * Ncols + col] = (OutT)f2bf(v);
      }
    }
  }
}

// ---------------------------------------------------------------------------
// Spatial attention, MFMA version. One block per (b,t,h), 8 waves.
// LDS was already >80KB so 4-wave ran at 1 block/CU = 1 wave/SIMD with zero
// latency hiding; 8 waves gives 2 waves/SIMD, halves staging time, and cuts
// worst-case tiles/wave 4 -> 2.
// LDS: Ks 29.9K + Vt 29.7K + Ps 59.4K = 119.0 KB (< 160 KB).
// Pad cols masked to -inf pre-max; V^T/P pad cols zeroed so 0*garbage can't
// produce NaN. Frag layouts verified end-to-end in earlier session rounds.
// ---------------------------------------------------------------------------
__global__ __launch_bounds__(512) void fsta_spatial(
    const ushort_t* __restrict__ qkv, ushort_t* __restrict__ x1)
{
  __shared__ ushort_t Ks[NP_ * KS_];       // [key][dim]   29,952 B
  __shared__ ushort_t Vt[64 * VS_];        // [dim][key]   29,696 B
  __shared__ ushort_t Ps[8][16 * PS_];     // per-wave P   59,392 B
  const int tid = threadIdx.x;
  const int bid = blockIdx.x;
  const int h   = bid % H_;
  const int bt  = bid / H_;
  const size_t rowbase = (size_t)bt * N_ * C3_;
  const int hofs = h * 64;

  // stage K row-major and V transposed
  for (int idx = tid; idx < N_ * 8; idx += 512) {
    int n = idx >> 3, c = (idx & 7) * 8;
    size_t so = rowbase + (size_t)n * C3_ + hofs + c;
    *(uint4*)&Ks[n * KS_ + c] = *(const uint4*)(qkv + so + 768);
    uint4 v = *(const uint4*)(qkv + so + 1536);
    ushort_t tmp[8];
    *(uint4*)tmp = v;
#pragma unroll
    for (int i = 0; i < 8; ++i) Vt[(c + i) * VS_ + n] = tmp[i];
  }
  // zero V^T pad cols 196..231
  for (int idx = tid; idx < 64 * (VS_ - N_); idx += 512) {
    int d = idx / (VS_ - N_), k = N_ + idx % (VS_ - N_);
    Vt[d * VS_ + k] = 0;
  }
  __syncthreads();

  const int lane = tid & 63;
  const int wv   = tid >> 6;
  const int lrow = lane & 15;
  const int quad = lane >> 4;
  const int k8   = quad * 8;

  for (int qt = wv; qt < 13; qt += 8) {
    // Q A-frags straight from global (rows clamped; results discarded at store)
    int qrow = qt * 16 + lrow; if (qrow > N_ - 1) qrow = N_ - 1;
    const ushort_t* qp = qkv + rowbase + (size_t)qrow * C3_ + hofs;
    short8 qf0 = *(const short8*)(qp + k8);
    short8 qf1 = *(const short8*)(qp + 32 + k8);

    // S = Q K^T : 13 key tiles, K-dim 64 = 2 MFMA steps
    floatx4 s[13];
#pragma unroll
    for (int kt = 0; kt < 13; ++kt) {
      const ushort_t* kp = &Ks[(kt * 16 + lrow) * KS_];
      short8 kf0 = *(const short8*)(kp + k8);
      short8 kf1 = *(const short8*)(kp + 32 + k8);
      floatx4 a = (floatx4){0.f, 0.f, 0.f, 0.f};
      a = __builtin_amdgcn_mfma_f32_16x16x32_bf16(qf0, kf0, a, 0, 0, 0);
      a = __builtin_amdgcn_mfma_f32_16x16x32_bf16(qf1, kf1, a, 0, 0, 0);
      s[kt] = a;
    }

    // mask pad cols (tile 12, cols 196..207) before max
    if (lrow >= 4)
      s[12] = (floatx4){-INFINITY, -INFINITY, -INFINITY, -INFINITY};

    // row max + exp + row sum (rows = quad*4+r, cols spread over 16 lanes)
    float mx[4], sum[4];
#pragma unroll
    for (int r = 0; r < 4; ++r) {
      float m2 = s[0][r];
#pragma unroll
      for (int kt = 1; kt < 13; ++kt) m2 = fmaxf(m2, s[kt][r]);
#pragma unroll
      for (int xm = 1; xm < 16; xm <<= 1) m2 = fmaxf(m2, __shfl_xor(m2, xm, 64));
      mx[r] = m2;
    }
#pragma unroll
    for (int r = 0; r < 4; ++r) {
      float sm = 0.f;
#pragma unroll
      for (int kt = 0; kt < 13; ++kt) {
        float p = __expf((s[kt][r] - mx[r]) * 0.125f);   // scale folded in
        s[kt][r] = p;
        sm += p;
      }
#pragma unroll
      for (int xm = 1; xm < 16; xm <<= 1) sm += __shfl_xor(sm, xm, 64);
      sum[r] = sm;
    }

    // P: C/D layout -> LDS (bf16), pad cols 208..223 zeroed
    ushort_t* pw = Ps[wv];
#pragma unroll
    for (int kt = 0; kt < 13; ++kt)
#pragma unroll
      for (int r = 0; r < 4; ++r)
        pw[(quad * 4 + r) * PS_ + kt * 16 + lrow] = f2bf(s[kt][r]);
#pragma unroll
    for (int r = 0; r < 4; ++r)
      pw[(quad * 4 + r) * PS_ + 208 + lrow] = 0;

    // O = P V : A-frag from Ps, B-frag from Vt, 7 k-steps of 32 (224 cols)
    floatx4 o[4];
#pragma unroll
    for (int nt = 0; nt < 4; ++nt) o[nt] = (floatx4){0.f, 0.f, 0.f, 0.f};
#pragma unroll
    for (int kt = 0; kt < 7; ++kt) {
      short8 pf = *(const short8*)&pw[lrow * PS_ + kt * 32 + k8];
#pragma unroll
      for (int nt = 0; nt < 4; ++nt) {
        short8 vf = *(const short8*)&Vt[(nt * 16 + lrow) * VS_ + kt * 32 + k8];
        o[nt] = __builtin_amdgcn_mfma_f32_16x16x32_bf16(pf, vf, o[nt], 0, 0, 0);
      }
    }

    // normalize + store (D rows quad*4+r match sum[r] lanes)
    float inv[4];
#pragma unroll
    for (int r = 0; r < 4; ++r) inv[r] = 1.f / sum[r];
#pragma unroll
    for (int nt = 0; nt < 4; ++nt) {
#pragma unroll
      for (int r = 0; r < 4; ++r) {
        int qr = qt * 16 + quad * 4 + r;
        if (qr < N_)
          x1[(size_t)(bt * N_ + qr) * C_ + hofs + nt * 16 + lrow] =
              f2bf(o[nt][r] * inv[r]);
      }
    }
  }
}

// ---------------------------------------------------------------------------
// Temporal attention, MFMA version. One WAVE per (b,h,n); T=16 rows, hd=64.
// Replaces the scalar one-thread-per-(b,h,n,t) kernel (3072 scalar FMAs/lane,
// ~200 VGPR) with 6 MFMAs/wave + 16-lane shfl softmax.
//   S[t][s] = mfma(Qfrag, Kfrag) over 2 k-steps (Q,K rows straight from
//   global, row index = lrow, same frag pattern as the verified GEMM).
//   Softmax over s = over the 16 lanes of each quad group (T=16, no pad).
//   P round-trips through a per-wave 16x40 LDS tile (C/D -> A-frag layout,
//   cols 16..31 zeroed so the single K=32 PV step is exact).
//   V^T staged per-wave [64][40] (stride 40 elems = 2-way bank alias, free).
// Fuses avg: reads spatial x1 and writes 0.5*(x1+x2) back into same buffer.
// No __syncthreads needed: all LDS tiles are wave-private.
// ---------------------------------------------------------------------------
__global__ __launch_bounds__(256) void fsta_temporal(
    const ushort_t* __restrict__ qkv, ushort_t* __restrict__ xavg)
{
  __shared__ ushort_t Pt[4][16 * TS_];   // per-wave P   [t][s]   1,280 B each
  __shared__ ushort_t Vw[4][64 * TS_];   // per-wave V^T [d][s]   5,120 B each
  const int tid  = threadIdx.x;
  const int lane = tid & 63;
  const int wv   = tid >> 6;
  const int gw   = blockIdx.x * 4 + wv;    // global wave id = (b,h,n)
  const int n    = gw % N_;
  const int bh   = gw / N_;
  const int h    = bh % H_;
  const int b    = bh / H_;
  const int hofs = h * 64;
  const int lrow = lane & 15;
  const int quad = lane >> 4;
  const int k8   = quad * 8;

  ushort_t* pw = Pt[wv];
  ushort_t* vw = Vw[wv];

  // zero pad cols s=16..31 of P and V^T (K=32 MFMA step covers 16 real + 16 zero)
  for (int i = lane; i < 16 * 16; i += 64)
    pw[(i >> 4) * TS_ + 16 + (i & 15)] = 0;
  for (int i = lane; i < 64 * 16; i += 64)
    vw[(i >> 4) * TS_ + 16 + (i & 15)] = 0;

  // stage V^T: V rows s=0..15 (64 dims) -> vw[d][s]
  for (int i = lane; i < 128; i += 64) {
    int s = i >> 3, c8 = (i & 7) * 8;
    size_t vo = ((size_t)((b * T_ + s) * N_ + n)) * C3_ + hofs + 1536 + c8;
    ushort_t tmp[8];
    *(uint4*)tmp = *(const uint4*)(qkv + vo);
#pragma unroll
    for (int j = 0; j < 8; ++j) vw[(c8 + j) * TS_ + s] = tmp[j];
  }

  // Q (A-frag, row t=lrow) and K (B-frag, row s=lrow) straight from global
  const size_t ro = ((size_t)((b * T_ + lrow) * N_ + n)) * C3_ + hofs;
  short8 qf0 = *(const short8*)(qkv + ro + k8);
  short8 qf1 = *(const short8*)(qkv + ro + 32 + k8);
  short8 kf0 = *(const short8*)(qkv + ro + 768 + k8);
  short8 kf1 = *(const short8*)(qkv + ro + 800 + k8);

  // S = Q K^T : C layout row = quad*4+r (t), col = lrow (s)
  floatx4 s4 = (floatx4){0.f, 0.f, 0.f, 0.f};
  s4 = __builtin_amdgcn_mfma_f32_16x16x32_bf16(qf0, kf0, s4, 0, 0, 0);
  s4 = __builtin_amdgcn_mfma_f32_16x16x32_bf16(qf1, kf1, s4, 0, 0, 0);

  // softmax over the 16 cols (one per lane within the quad group)
  float inv[4];
#pragma unroll
  for (int r = 0; r < 4; ++r) {
    float m2 = s4[r];
#pragma unroll
    for (int xm = 1; xm < 16; xm <<= 1) m2 = fmaxf(m2, __shfl_xor(m2, xm, 64));
    float p = __expf((s4[r] - m2) * 0.125f);   // scale folded in
    float sm = p;
#pragma unroll
    for (int xm = 1; xm < 16; xm <<= 1) sm += __shfl_xor(sm, xm, 64);
    pw[(quad * 4 + r) * TS_ + lrow] = f2bf(p);
    inv[r] = 1.f / sm;
  }

  // O = P V : A-frag from Pt (rows t=lrow), B-frag from Vw; one K=32 step
  short8 pf = *(const short8*)&pw[lrow * TS_ + k8];
  floatx4 o[4];
#pragma unroll
  for (int nt = 0; nt < 4; ++nt) {
    short8 vf = *(const short8*)&vw[(nt * 16 + lrow) * TS_ + k8];
    o[nt] = __builtin_amdgcn_mfma_f32_16x16x32_bf16(
        pf, vf, (floatx4){0.f, 0.f, 0.f, 0.f}, 0, 0, 0);
  }

  // normalize + fused 0.5*(x1+x2): C rows quad*4+r = t, cols nt*16+lrow = d
#pragma unroll
  for (int nt = 0; nt < 4; ++nt)
#pragma unroll
    for (int r = 0; r < 4; ++r) {
      int t = quad * 4 + r;
      size_t xo = ((size_t)((b * T_ + t) * N_ + n)) * C_ + hofs + nt * 16 + lrow;
      float prev = bf2f(xavg[xo]);
      xavg[xo] = f2bf(0.5f * (prev + o[nt][r] * inv[r]));
    }
}

// ---------------------------------------------------------------------------
// ws layout (bf16 elements):
//   WtQkv  @ 0          : 2304*768   = 1,769,472
//   WtProj @ 1,769,472  : 768*768    =   589,824
//   xbf    @ 2,359,296  : 25088*768  = 19,267,584   (aliased as xavg later)
//   qkv    @ 21,626,880 : 25088*2304 = 57,802,752
// total 79,429,632 elems = 158.9 MB
// Inputs fp32, output fp32, internal compute bf16 MFMA.
// ---------------------------------------------------------------------------
extern "C" void kernel_launch(void* const* d_in, const int* in_sizes, int n_in,
                              void* d_out, int out_size, void* d_ws, size_t ws_size,
                              hipStream_t stream)
{
  (void)in_sizes; (void)n_in; (void)out_size; (void)ws_size;
  const float* x     = (const float*)d_in[0];
  const float* Wqkv  = (const float*)d_in[1];
  const float* Wproj = (const float*)d_in[2];
  const float* bproj = (const float*)d_in[3];
  float*    out = (float*)d_out;
  ushort_t* ws  = (ushort_t*)d_ws;

  ushort_t* WtQkv  = ws;
  ushort_t* WtProj = ws + 1769472;
  ushort_t* xbf    = ws + 2359296;   // also xavg after spatial
  ushort_t* xavg   = xbf;
  ushort_t* qkv    = ws + 21626880;

  // 1. fused prep: x -> bf16, W_qkv / W_proj -> transposed bf16
  fsta_prep<<<dim3(18624), dim3(256), 0, stream>>>(
      x, xbf, Wqkv, WtQkv, Wproj, WtProj);
  // 2. qkv = x @ W_qkv   : M=25088, N=2304, K=768   (bf16 out)
  fsta_gemm_bt<ushort_t><<<dim3(196, 18), dim3(256), 0, stream>>>(
      xbf, WtQkv, (const float*)nullptr, qkv, 2304, 768);
  // 3. spatial attention (MFMA, 8 waves) -> xavg (holds x1; aliases dead xbf)
  fsta_spatial<<<dim3(B_ * T_ * H_), dim3(512), 0, stream>>>(qkv, xavg);
  // 4. temporal attention (MFMA, 1 wave per (b,h,n)), fused 0.5*(x1+x2)
  fsta_temporal<<<dim3((B_ * H_ * N_) / 4), dim3(256), 0, stream>>>(qkv, xavg);
  // 5. out = xavg @ W_proj + b_proj : M=25088, N=768, K=768  (fp32 out)
  fsta_gemm_bt<float><<<dim3(196, 6), dim3(256), 0, stream>>>(
      xavg, WtProj, bproj, out, 768, 768);
}

// Round 3
// 426.927 us; speedup vs baseline: 1.0449x; 1.0449x over previous
//
#include <hip/hip_runtime.h>
#include <cstdint>
#include <cstddef>

typedef unsigned short ushort_t;
typedef unsigned int   uint_t;

#define B_   8
#define T_   16
#define N_   196
#define C_   768
#define H_   12
#define C3_  2304
#define M_   25088   // B_*T_*N_

// spatial-attention tiling
#define NP_  208     // N padded to 13 tiles of 16
#define KS_  72      // K LDS row stride (elems): 144 B, 16B-aligned, 2-way alias
#define VS_  232     // V^T LDS row stride: 464 B, 16B-aligned, 2-way alias
#define PS_  232     // P LDS row stride

// temporal-attention tiling
#define TS_  40      // LDS row stride (elems): 80 B, 16B-aligned, 2-way alias

typedef __attribute__((ext_vector_type(8))) short short8;
typedef __attribute__((ext_vector_type(4))) float floatx4;

__device__ __forceinline__ float bf2f(ushort_t u) {
  return __uint_as_float(((uint_t)u) << 16);
}
__device__ __forceinline__ ushort_t f2bf(float f) {
  uint_t u = __float_as_uint(f);
  u += 0x7FFFu + ((u >> 16) & 1u);   // round-to-nearest-even
  return (ushort_t)(u >> 16);
}
__device__ __forceinline__ uint_t pack2(float a, float b) {
  return (uint_t)f2bf(a) | ((uint_t)f2bf(b) << 16);
}

// async global->LDS, 16 B per lane. LDS dest = wave-uniform base + lane*16.
__device__ __forceinline__ void gload_lds16(const ushort_t* g, ushort_t* l) {
  __builtin_amdgcn_global_load_lds(
      (const __attribute__((address_space(1))) uint_t*)g,
      (__attribute__((address_space(3))) uint_t*)l, 16, 0, 0);
}

// raw barrier: compiler memory fence + s_barrier + scheduler pin.
// (NOT __syncthreads(): that drains vmcnt(0) and would kill the counted
// prefetch pipeline.)
__device__ __forceinline__ void bar() {
  asm volatile("" ::: "memory");
  __builtin_amdgcn_s_barrier();
  __builtin_amdgcn_sched_barrier(0);
}

// ---------------------------------------------------------------------------
// Fused prep (one dispatch):
//   blocks [0, 9408)        : x fp32 -> bf16, 8 elems/thread (19,267,584)
//   blocks [9408, 16320)    : W_qkv [768][2304] -> transposed bf16 [2304][768]
//   blocks [16320, 18624)   : W_proj [768][768] -> transposed bf16 [768][768]
// ---------------------------------------------------------------------------
__global__ void fsta_prep(const float* __restrict__ x,
                          ushort_t* __restrict__ xbf,
                          const float* __restrict__ Wqkv,
                          ushort_t* __restrict__ WtQkv,
                          const float* __restrict__ Wproj,
                          ushort_t* __restrict__ WtProj)
{
  const int bid = blockIdx.x;
  const int tid = threadIdx.x;
  if (bid < 9408) {
    int i = (bid * 256 + tid) * 8;
    const float* f = x + i;
    uint4 u;
    u.x = pack2(f[0], f[1]); u.y = pack2(f[2], f[3]);
    u.z = pack2(f[4], f[5]); u.w = pack2(f[6], f[7]);
    *(uint4*)(xbf + i) = u;
  } else if (bid < 16320) {
    int o = (bid - 9408) * 256 + tid;           // < 1,769,472
    int c = o / 768;
    int r = o - c * 768;
    WtQkv[o] = f2bf(Wqkv[(size_t)r * 2304 + c]);
  } else {
    int o = (bid - 16320) * 256 + tid;          // < 589,824
    int c = o / 768;
    int r = o - c * 768;
    WtProj[o] = f2bf(Wproj[(size_t)r * 768 + c]);
  }
}

// ---------------------------------------------------------------------------
// 256x256 8-phase bf16 MFMA GEMM (T1+T2+T3+T4+T5 port):
//   C[M,N] = A[M,K] @ Bt[N,K]^T (+ fp32 bias)
// 8 waves (2Mx4N), BK=64, per-wave output 128x64, acc[8][4] of 16x16x32.
// LDS 128 KiB = 2 buffers x {A[2 ks-halves][256][32], B[...]}  (even K-tiles
// in buf0, odd in buf1). Each phase: {ds_read subtile | stage prefetch |
// (vmcnt guard at p4/p8) | barrier | 16 MFMA in setprio(1) | barrier}.
//
// Region-liveness prefetch schedule (per iteration i, tiles t0=2i, t0+1):
//   p1 reads (buf0,ks0), stages tile t0+1 ks1 -> (buf1,ks1)   [dead since p1]
//   p3 reads (buf0,ks1), stages A of t0+2 ks0 -> (buf0,ks0)   [dead since p3]
//   p4 stages B of t0+2 ks0; vmcnt(4) -> everything up to p1 landed
//   p5 reads (buf1,ks0), stages t0+2 ks1 -> (buf0,ks1)        [dead since p5]
//   p7 reads (buf1,ks1), stages A of t0+3 ks0 -> (buf1,ks0)   [dead since p7]
//   p8 stages B of t0+3 ks0; vmcnt(4) -> everything up to p5 landed
// Every region is staged >=4 phases before its reads, and the guard that
// covers those reads executes before the phase that issues them. Last
// iteration skips t0+2/t0+3 stages and drains with vmcnt(0) at p4.
//
// T2 swizzle: row r of a [256][32] region stores 16B-chunk c at slot
// c^(r&3) (4-way conflict floor instead of 16-way). gload_lds writes
// linearly, so the *global source* chunk is pre-inverse-swizzled
// ((lane&3)^(srow&3)) and ds_read uses slot (quad^(lrow&3)) [rule #21].
// ---------------------------------------------------------------------------
#define STG(X, rb, bu, xo, kss, t)                                            \
  { _Pragma("unroll") for (int c_ = 0; c_ < 2; ++c_) {                        \
      const ushort_t* g_ = (X) +                                              \
          (size_t)((rb) + c_ * 128 + wv * 16 + srow) * K +                    \
          (t) * 64 + (kss) * 32 + chnk * 8;                                   \
      gload_lds16(g_, &lds[(bu) * 32768 + (xo) + (kss) * 8192 +               \
                           c_ * 4096 + wv * 512]); } }

#define PH(bu, mh, kss, DOB, GUARD, ...)                                      \
  { short8 af[4];                                                             \
    _Pragma("unroll") for (int m2 = 0; m2 < 4; ++m2) {                        \
      int rr = wm * 128 + ((mh) * 4 + m2) * 16 + lrow;                        \
      af[m2] = *(const short8*)&lds[(bu) * 32768 + (kss) * 8192 +             \
                                    rr * 32 + rch8]; }                        \
    if (DOB) {                                                                \
      _Pragma("unroll") for (int n2 = 0; n2 < 4; ++n2) {                      \
        int rr = wn * 64 + n2 * 16 + lrow;                                    \
        bf[n2] = *(const short8*)&lds[(bu) * 32768 + 16384 + (kss) * 8192 +   \
                                      rr * 32 + rch8]; } }                    \
    __VA_ARGS__                                                               \
    GUARD                                                                     \
    bar();                                                                    \
    __builtin_amdgcn_s_setprio(1);                                            \
    _Pragma("unroll") for (int m2 = 0; m2 < 4; ++m2)                          \
      _Pragma("unroll") for (int n2 = 0; n2 < 4; ++n2)                        \
        acc[(mh) * 4 + m2][n2] = __builtin_amdgcn_mfma_f32_16x16x32_bf16(     \
            af[m2], bf[n2], acc[(mh) * 4 + m2][n2], 0, 0, 0);                 \
    __builtin_amdgcn_s_setprio(0);                                            \
    bar(); }

#define GUARD_NONE
#define GUARD4 asm volatile("s_waitcnt vmcnt(4)" ::: "memory");
#define GUARD0 asm volatile("s_waitcnt vmcnt(0)" ::: "memory");

template <typename OutT>
__global__ __launch_bounds__(512) void fsta_gemm256(
    const ushort_t* __restrict__ A1,
    const ushort_t* __restrict__ Bt,
    const float* __restrict__ bias,
    OutT* __restrict__ Cout,
    int Ncols, int K)
{
  __shared__ ushort_t lds[65536];          // 128 KiB
  const int tid  = threadIdx.x;
  const int lane = tid & 63;
  const int wv   = tid >> 6;
  const int wm   = wv >> 2;                // 0..1 (M half)
  const int wn   = wv & 3;                 // 0..3 (N quarter)
  const int lrow = lane & 15;
  const int quad = lane >> 4;
  const int rch8 = (quad ^ (lrow & 3)) * 8;        // swizzled read chunk (elems)
  const int srow = lane >> 2;                       // staging row-in-16
  const int chnk = (lane & 3) ^ (srow & 3);         // inverse-swizzled src chunk

  // bijective XCD-chunk swizzle (m204 formula; grids 882 / 294, neither %8==0)
  const int ntx = gridDim.x;
  const int nwg = ntx * gridDim.y;
  int lin = blockIdx.y * ntx + blockIdx.x;
  {
    int q = nwg >> 3, r = nwg & 7;
    int xcd = lin & 7, off = lin >> 3;
    lin = (xcd < r ? xcd * (q + 1) : r * (q + 1) + (xcd - r) * q) + off;
  }
  const int m0 = (lin % ntx) * 256;
  const int n0 = (lin / ntx) * 256;

  const int NT = K >> 6;                   // 64-wide K-tiles (12)
  const int NI = NT >> 1;                  // iterations (6)

  floatx4 acc[8][4];
#pragma unroll
  for (int i = 0; i < 8; ++i)
#pragma unroll
    for (int j = 0; j < 4; ++j)
      acc[i][j] = (floatx4){0.f, 0.f, 0.f, 0.f};

  // prologue: tile0 (both ks halves) + tile1 ks0; leave tile1-ks0 in flight
  STG(A1, m0, 0, 0,     0, 0)
  STG(Bt, n0, 0, 16384, 0, 0)
  STG(A1, m0, 0, 0,     1, 0)
  STG(Bt, n0, 0, 16384, 1, 0)
  STG(A1, m0, 1, 0,     0, 1)
  STG(Bt, n0, 1, 16384, 0, 1)
  GUARD4                                   // tile0 fully landed
  bar();

  short8 bf[4];                            // B-frags persist across mh phases
  for (int i = 0; i < NI; ++i) {
    const int t0 = 2 * i;
    const bool lastI = (i == NI - 1);
    // p1: (buf0,ks0) mh0 | stage tile t0+1 ks1 -> buf1
    PH(0, 0, 0, 1, GUARD_NONE,
       { STG(A1, m0, 1, 0, 1, t0 + 1) STG(Bt, n0, 1, 16384, 1, t0 + 1) })
    // p2: (buf0,ks0) mh1
    PH(0, 1, 0, 0, GUARD_NONE, )
    // p3: (buf0,ks1) mh0 | stage A of tile t0+2 ks0 -> buf0
    PH(0, 0, 1, 1, GUARD_NONE,
       { if (!lastI) { STG(A1, m0, 0, 0, 0, t0 + 2) } })
    // p4: (buf0,ks1) mh1 | stage B of tile t0+2 ks0 | guard
    PH(0, 1, 1, 0, if (lastI) { GUARD0 } else { GUARD4 },
       { if (!lastI) { STG(Bt, n0, 0, 16384, 0, t0 + 2) } })
    // p5: (buf1,ks0) mh0 | stage tile t0+2 ks1 -> buf0
    PH(1, 0, 0, 1, GUARD_NONE,
       { if (!lastI) { STG(A1, m0, 0, 0, 1, t0 + 2)
                       STG(Bt, n0, 0, 16384, 1, t0 + 2) } })
    // p6: (buf1,ks0) mh1
    PH(1, 1, 0, 0, GUARD_NONE, )
    // p7: (buf1,ks1) mh0 | stage A of tile t0+3 ks0 -> buf1
    PH(1, 0, 1, 1, GUARD_NONE,
       { if (!lastI) { STG(A1, m0, 1, 0, 0, t0 + 3) } })
    // p8: (buf1,ks1) mh1 | stage B of tile t0+3 ks0 | guard
    PH(1, 1, 1, 0, if (!lastI) { GUARD4 },
       { if (!lastI) { STG(Bt, n0, 1, 16384, 0, t0 + 3) } })
  }

  // epilogue: C/D layout col=lane&15, row=quad*4+reg
#pragma unroll
  for (int m2 = 0; m2 < 8; ++m2) {
    int row = m0 + wm * 128 + m2 * 16 + quad * 4;
#pragma unroll
    for (int n2 = 0; n2 < 4; ++n2) {
      int col = n0 + wn * 64 + n2 * 16 + lrow;
      float badd = bias ? bias[col] : 0.f;
#pragma unroll
      for (int rr = 0; rr < 4; ++rr) {
        float v = acc[m2][n2][rr] + badd;
        if constexpr (sizeof(OutT) == 4)
          Cout[(size_t)(row + rr) * Ncols + col] = v;
        else
          Cout[(size_t)(row + rr) * Ncols + col] = (OutT)f2bf(v);
      }
    }
  }
}

// ---------------------------------------------------------------------------
// Spatial attention, MFMA version. One block per (b,t,h), 8 waves.
// LDS: Ks 29.9K + Vt 29.7K + Ps 59.4K = 119.0 KB -> 1 block/CU, 2 waves/SIMD.
// ---------------------------------------------------------------------------
__global__ __launch_bounds__(512) void fsta_spatial(
    const ushort_t* __restrict__ qkv, ushort_t* __restrict__ x1)
{
  __shared__ ushort_t Ks[NP_ * KS_];       // [key][dim]   29,952 B
  __shared__ ushort_t Vt[64 * VS_];        // [dim][key]   29,696 B
  __shared__ ushort_t Ps[8][16 * PS_];     // per-wave P   59,392 B
  const int tid = threadIdx.x;
  const int bid = blockIdx.x;
  const int h   = bid % H_;
  const int bt  = bid / H_;
  const size_t rowbase = (size_t)bt * N_ * C3_;
  const int hofs = h * 64;

  // stage K row-major and V transposed
  for (int idx = tid; idx < N_ * 8; idx += 512) {
    int n = idx >> 3, c = (idx & 7) * 8;
    size_t so = rowbase + (size_t)n * C3_ + hofs + c;
    *(uint4*)&Ks[n * KS_ + c] = *(const uint4*)(qkv + so + 768);
    uint4 v = *(const uint4*)(qkv + so + 1536);
    ushort_t tmp[8];
    *(uint4*)tmp = v;
#pragma unroll
    for (int i = 0; i < 8; ++i) Vt[(c + i) * VS_ + n] = tmp[i];
  }
  // zero V^T pad cols 196..231
  for (int idx = tid; idx < 64 * (VS_ - N_); idx += 512) {
    int d = idx / (VS_ - N_), k = N_ + idx % (VS_ - N_);
    Vt[d * VS_ + k] = 0;
  }
  __syncthreads();

  const int lane = tid & 63;
  const int wv   = tid >> 6;
  const int lrow = lane & 15;
  const int quad = lane >> 4;
  const int k8   = quad * 8;

  for (int qt = wv; qt < 13; qt += 8) {
    // Q A-frags straight from global (rows clamped; results discarded at store)
    int qrow = qt * 16 + lrow; if (qrow > N_ - 1) qrow = N_ - 1;
    const ushort_t* qp = qkv + rowbase + (size_t)qrow * C3_ + hofs;
    short8 qf0 = *(const short8*)(qp + k8);
    short8 qf1 = *(const short8*)(qp + 32 + k8);

    // S = Q K^T : 13 key tiles, K-dim 64 = 2 MFMA steps
    floatx4 s[13];
#pragma unroll
    for (int kt = 0; kt < 13; ++kt) {
      const ushort_t* kp = &Ks[(kt * 16 + lrow) * KS_];
      short8 kf0 = *(const short8*)(kp + k8);
      short8 kf1 = *(const short8*)(kp + 32 + k8);
      floatx4 a = (floatx4){0.f, 0.f, 0.f, 0.f};
      a = __builtin_amdgcn_mfma_f32_16x16x32_bf16(qf0, kf0, a, 0, 0, 0);
      a = __builtin_amdgcn_mfma_f32_16x16x32_bf16(qf1, kf1, a, 0, 0, 0);
      s[kt] = a;
    }

    // mask pad cols (tile 12, cols 196..207) before max
    if (lrow >= 4)
      s[12] = (floatx4){-INFINITY, -INFINITY, -INFINITY, -INFINITY};

    // row max + exp + row sum (rows = quad*4+r, cols spread over 16 lanes)
    float mx[4], sum[4];
#pragma unroll
    for (int r = 0; r < 4; ++r) {
      float m2 = s[0][r];
#pragma unroll
      for (int kt = 1; kt < 13; ++kt) m2 = fmaxf(m2, s[kt][r]);
#pragma unroll
      for (int xm = 1; xm < 16; xm <<= 1) m2 = fmaxf(m2, __shfl_xor(m2, xm, 64));
      mx[r] = m2;
    }
#pragma unroll
    for (int r = 0; r < 4; ++r) {
      float sm = 0.f;
#pragma unroll
      for (int kt = 0; kt < 13; ++kt) {
        float p = __expf((s[kt][r] - mx[r]) * 0.125f);   // scale folded in
        s[kt][r] = p;
        sm += p;
      }
#pragma unroll
      for (int xm = 1; xm < 16; xm <<= 1) sm += __shfl_xor(sm, xm, 64);
      sum[r] = sm;
    }

    // P: C/D layout -> LDS (bf16), pad cols 208..223 zeroed
    ushort_t* pw = Ps[wv];
#pragma unroll
    for (int kt = 0; kt < 13; ++kt)
#pragma unroll
      for (int r = 0; r < 4; ++r)
        pw[(quad * 4 + r) * PS_ + kt * 16 + lrow] = f2bf(s[kt][r]);
#pragma unroll
    for (int r = 0; r < 4; ++r)
      pw[(quad * 4 + r) * PS_ + 208 + lrow] = 0;

    // O = P V : A-frag from Ps, B-frag from Vt, 7 k-steps of 32 (224 cols)
    floatx4 o[4];
#pragma unroll
    for (int nt = 0; nt < 4; ++nt) o[nt] = (floatx4){0.f, 0.f, 0.f, 0.f};
#pragma unroll
    for (int kt = 0; kt < 7; ++kt) {
      short8 pf = *(const short8*)&pw[lrow * PS_ + kt * 32 + k8];
#pragma unroll
      for (int nt = 0; nt < 4; ++nt) {
        short8 vf = *(const short8*)&Vt[(nt * 16 + lrow) * VS_ + kt * 32 + k8];
        o[nt] = __builtin_amdgcn_mfma_f32_16x16x32_bf16(pf, vf, o[nt], 0, 0, 0);
      }
    }

    // normalize + store (D rows quad*4+r match sum[r] lanes)
    float inv[4];
#pragma unroll
    for (int r = 0; r < 4; ++r) inv[r] = 1.f / sum[r];
#pragma unroll
    for (int nt = 0; nt < 4; ++nt) {
#pragma unroll
      for (int r = 0; r < 4; ++r) {
        int qr = qt * 16 + quad * 4 + r;
        if (qr < N_)
          x1[(size_t)(bt * N_ + qr) * C_ + hofs + nt * 16 + lrow] =
              f2bf(o[nt][r] * inv[r]);
      }
    }
  }
}

// ---------------------------------------------------------------------------
// Temporal attention, MFMA version. One WAVE per (b,h,n); T=16 rows, hd=64.
// 6 MFMAs/wave + 16-lane shfl softmax; per-wave LDS tiles, no __syncthreads.
// Fuses avg: reads spatial x1 and writes 0.5*(x1+x2) back into same buffer.
// ---------------------------------------------------------------------------
__global__ __launch_bounds__(256) void fsta_temporal(
    const ushort_t* __restrict__ qkv, ushort_t* __restrict__ xavg)
{
  __shared__ ushort_t Pt[4][16 * TS_];   // per-wave P   [t][s]   1,280 B each
  __shared__ ushort_t Vw[4][64 * TS_];   // per-wave V^T [d][s]   5,120 B each
  const int tid  = threadIdx.x;
  const int lane = tid & 63;
  const int wv   = tid >> 6;
  const int gw   = blockIdx.x * 4 + wv;    // global wave id = (b,h,n)
  const int n    = gw % N_;
  const int bh   = gw / N_;
  const int h    = bh % H_;
  const int b    = bh / H_;
  const int hofs = h * 64;
  const int lrow = lane & 15;
  const int quad = lane >> 4;
  const int k8   = quad * 8;

  ushort_t* pw = Pt[wv];
  ushort_t* vw = Vw[wv];

  // zero pad cols s=16..31 of P and V^T (K=32 MFMA step = 16 real + 16 zero)
  for (int i = lane; i < 16 * 16; i += 64)
    pw[(i >> 4) * TS_ + 16 + (i & 15)] = 0;
  for (int i = lane; i < 64 * 16; i += 64)
    vw[(i >> 4) * TS_ + 16 + (i & 15)] = 0;

  // stage V^T: V rows s=0..15 (64 dims) -> vw[d][s]
  for (int i = lane; i < 128; i += 64) {
    int s = i >> 3, c8 = (i & 7) * 8;
    size_t vo = ((size_t)((b * T_ + s) * N_ + n)) * C3_ + hofs + 1536 + c8;
    ushort_t tmp[8];
    *(uint4*)tmp = *(const uint4*)(qkv + vo);
#pragma unroll
    for (int j = 0; j < 8; ++j) vw[(c8 + j) * TS_ + s] = tmp[j];
  }

  // Q (A-frag, row t=lrow) and K (B-frag, row s=lrow) straight from global
  const size_t ro = ((size_t)((b * T_ + lrow) * N_ + n)) * C3_ + hofs;
  short8 qf0 = *(const short8*)(qkv + ro + k8);
  short8 qf1 = *(const short8*)(qkv + ro + 32 + k8);
  short8 kf0 = *(const short8*)(qkv + ro + 768 + k8);
  short8 kf1 = *(const short8*)(qkv + ro + 800 + k8);

  // S = Q K^T : C layout row = quad*4+r (t), col = lrow (s)
  floatx4 s4 = (floatx4){0.f, 0.f, 0.f, 0.f};
  s4 = __builtin_amdgcn_mfma_f32_16x16x32_bf16(qf0, kf0, s4, 0, 0, 0);
  s4 = __builtin_amdgcn_mfma_f32_16x16x32_bf16(qf1, kf1, s4, 0, 0, 0);

  // softmax over the 16 cols (one per lane within the quad group)
  float inv[4];
#pragma unroll
  for (int r = 0; r < 4; ++r) {
    float m2 = s4[r];
#pragma unroll
    for (int xm = 1; xm < 16; xm <<= 1) m2 = fmaxf(m2, __shfl_xor(m2, xm, 64));
    float p = __expf((s4[r] - m2) * 0.125f);   // scale folded in
    float sm = p;
#pragma unroll
    for (int xm = 1; xm < 16; xm <<= 1) sm += __shfl_xor(sm, xm, 64);
    pw[(quad * 4 + r) * TS_ + lrow] = f2bf(p);
    inv[r] = 1.f / sm;
  }

  // O = P V : A-frag from Pt (rows t=lrow), B-frag from Vw; one K=32 step
  short8 pf = *(const short8*)&pw[lrow * TS_ + k8];
  floatx4 o[4];
#pragma unroll
  for (int nt = 0; nt < 4; ++nt) {
    short8 vf = *(const short8*)&vw[(nt * 16 + lrow) * TS_ + k8];
    o[nt] = __builtin_amdgcn_mfma_f32_16x16x32_bf16(
        pf, vf, (floatx4){0.f, 0.f, 0.f, 0.f}, 0, 0, 0);
  }

  // normalize + fused 0.5*(x1+x2): C rows quad*4+r = t, cols nt*16+lrow = d
#pragma unroll
  for (int nt = 0; nt < 4; ++nt)
#pragma unroll
    for (int r = 0; r < 4; ++r) {
      int t = quad * 4 + r;
      size_t xo = ((size_t)((b * T_ + t) * N_ + n)) * C_ + hofs + nt * 16 + lrow;
      float prev = bf2f(xavg[xo]);
      xavg[xo] = f2bf(0.5f * (prev + o[nt][r] * inv[r]));
    }
}

// ---------------------------------------------------------------------------
// ws layout (bf16 elements):
//   WtQkv  @ 0          : 2304*768   = 1,769,472
//   WtProj @ 1,769,472  : 768*768    =   589,824
//   xbf    @ 2,359,296  : 25088*768  = 19,267,584   (aliased as xavg later)
//   qkv    @ 21,626,880 : 25088*2304 = 57,802,752
// total 79,429,632 elems = 158.9 MB
// ---------------------------------------------------------------------------
extern "C" void kernel_launch(void* const* d_in, const int* in_sizes, int n_in,
                              void* d_out, int out_size, void* d_ws, size_t ws_size,
                              hipStream_t stream)
{
  (void)in_sizes; (void)n_in; (void)out_size; (void)ws_size;
  const float* x     = (const float*)d_in[0];
  const float* Wqkv  = (const float*)d_in[1];
  const float* Wproj = (const float*)d_in[2];
  const float* bproj = (const float*)d_in[3];
  float*    out = (float*)d_out;
  ushort_t* ws  = (ushort_t*)d_ws;

  ushort_t* WtQkv  = ws;
  ushort_t* WtProj = ws + 1769472;
  ushort_t* xbf    = ws + 2359296;   // also xavg after spatial
  ushort_t* xavg   = xbf;
  ushort_t* qkv    = ws + 21626880;

  // 1. fused prep: x -> bf16, W_qkv / W_proj -> transposed bf16
  fsta_prep<<<dim3(18624), dim3(256), 0, stream>>>(
      x, xbf, Wqkv, WtQkv, Wproj, WtProj);
  // 2. qkv = x @ W_qkv   : M=25088, N=2304, K=768   (bf16 out, 98x9 tiles)
  fsta_gemm256<ushort_t><<<dim3(98, 9), dim3(512), 0, stream>>>(
      xbf, WtQkv, (const float*)nullptr, qkv, 2304, 768);
  // 3. spatial attention (MFMA, 8 waves) -> xavg (holds x1; aliases dead xbf)
  fsta_spatial<<<dim3(B_ * T_ * H_), dim3(512), 0, stream>>>(qkv, xavg);
  // 4. temporal attention (MFMA, 1 wave per (b,h,n)), fused 0.5*(x1+x2)
  fsta_temporal<<<dim3((B_ * H_ * N_) / 4), dim3(256), 0, stream>>>(qkv, xavg);
  // 5. out = xavg @ W_proj + b_proj : M=25088, N=768, K=768  (fp32, 98x3 tiles)
  fsta_gemm256<float><<<dim3(98, 3), dim3(512), 0, stream>>>(
      xavg, WtProj, bproj, out, 768, 768);
}